// Round 1
// baseline (130.316 us; speedup 1.0000x reference)
//
#include <hip/hip_runtime.h>
#include <hip/hip_fp16.h>

// Problem constants (B,C,D,H,W) = (2,4,96,160,160)
#define NB 2
#define NC 4
#define ND 96
#define NH 160
#define NW 160

// Math (verified exact rounds 1-7): sy == sz (identical 2D 3x3 kernels),
// depth padding adds only zero slices, sobel(p)-sobel(t) = sobel(q) with
// q = softmax(pred) - onehot(target):
//   loss = sum(gx^2 + 2*gy^2) * SCALE
// separable: d = q[x+1]-q[x-1], s = q[x-1]+2q[x]+q[x+1],
//            gx = d[y-1]+2d[y]+d[y+1], gy = s[y+1]-s[y-1].
//
// Perf history:
//  r4/r5: __launch_bounds__(256,6) VGPR cap -> 128 MB scratch spill. Fixed:
//         never add an occupancy floor here.
//  r2..r6: dur == #same-address-atomicAdds x ~20ns -> single-address atomics
//         serialize cross-XCD. NEVER one-atomic-per-block (3072 x 20ns = 60us
//         chain); plain per-block stores + tiny reduce kernel instead.
//  r8:    fp16-packed LDS class-pair planes, conflict-free b128 staging,
//         packed-half Sobel -> ~29us boundary kernel.
//  r9 (this): timed region = 2x300MiB harness ws-poison fills (~94us,
//         untouchable) + our ~35us. Remaining lever: boundary is at ~65% of
//         streaming BW. TH=10 (halo 1.25x->1.2x) + XCD-chunked swizzle so
//         vertically-adjacent bands co-reside on one XCD and halo rows hit
//         that XCD's L2 (poison fills flush L3 every iteration, so cross-XCD
//         halo re-reads were HBM/L3 round-trips).
constexpr int TH    = 10;             // output rows per band
constexpr int SR    = TH + 2;         // 12 staged rows (vertical halo)
constexpr int NBAND = NH / TH;        // 16 bands per slice
constexpr int NSLOT = SR * NW / 4;    // 480 4-pixel staging slots
constexpr int PCELL = SR * NW;        // 1920 px cells per plane
constexpr int ZCELL = PCELL;          // always-zero guard cell (x-boundary)
constexpr int NBLK  = NBAND * NB * ND;           // 3072 blocks / partials
constexpr int NXCD  = 8;
constexpr int CHUNK = NBLK / NXCD;    // 384 (NBLK % 8 == 0 -> bijective)
constexpr float SCALE = 1.0f / (2.0f * 98.0f * 162.0f * 162.0f * 4.0f);

__device__ __forceinline__ __half2 ld_h2(const unsigned int* p, int i) {
    return __builtin_bit_cast(__half2, p[i]);
}

// One pixel: softmax over 4 class logits minus onehot(target), packed as
// two half2 (classes 01 -> a, classes 23 -> b).
__device__ __forceinline__ void qcalc(float p0, float p1, float p2, float p3,
                                      int t, bool valid,
                                      unsigned int& ha, unsigned int& hb) {
    float q0 = 0.f, q1 = 0.f, q2 = 0.f, q3 = 0.f;
    if (valid) {
        const float m  = fmaxf(fmaxf(p0, p1), fmaxf(p2, p3));
        const float e0 = __expf(p0 - m);
        const float e1 = __expf(p1 - m);
        const float e2 = __expf(p2 - m);
        const float e3 = __expf(p3 - m);
        const float inv = 1.0f / (e0 + e1 + e2 + e3);
        q0 = e0 * inv - (t == 0 ? 1.f : 0.f);
        q1 = e1 * inv - (t == 1 ? 1.f : 0.f);
        q2 = e2 * inv - (t == 2 ? 1.f : 0.f);
        q3 = e3 * inv - (t == 3 ? 1.f : 0.f);
    }
    ha = __builtin_bit_cast(unsigned int, __floats2half2_rn(q0, q1));
    hb = __builtin_bit_cast(unsigned int, __floats2half2_rn(q2, q3));
}

__global__ __launch_bounds__(256) void boundary_loss_kernel(
    const float* __restrict__ pred,   // (B,C,D,H,W) f32
    const int*   __restrict__ target, // (B,D,H,W) i32
    float* __restrict__ part)         // NBLK per-block partials
{
    __shared__ unsigned int pa[PCELL + 4];  // classes 0,1 packed half2
    __shared__ unsigned int pb[PCELL + 4];  // classes 2,3 packed half2
    __shared__ float wsum[4];

    const int tid = threadIdx.x;

    // XCD-chunked swizzle: hw block L lands on XCD L%8 (round-robin); give
    // each XCD a contiguous 384-block chunk (= 24 whole slices) so adjacent
    // bands of a slice share that XCD's L2 for their halo rows.
    const int lin   = blockIdx.x;
    const int lin2  = (lin & (NXCD - 1)) * CHUNK + (lin >> 3);
    const int band  = lin2 & (NBAND - 1);
    const int slice = lin2 >> 4;      // b*ND + d
    const int b     = slice / ND;
    const int d     = slice - b * ND;
    const int y0    = band * TH;

    const size_t cs4   = (size_t)ND * NH * NW / 4;   // class stride in float4
    const size_t pbase = ((size_t)b * NC * ND + d) * (size_t)(NH * NW);
    const size_t tbase = ((size_t)b * ND + d) * (size_t)(NH * NW);

    // ---- Load phase: slot A = tid, slot B = tid + 256 (tid < 224) ----
    const int  rA   = tid / 40;
    const int  cA   = tid - rA * 40;
    const int  gyA  = y0 - 1 + rA;
    const bool vA   = (gyA >= 0) && (gyA < NH);
    const int  gyAc = min(max(gyA, 0), NH - 1);

    const int  sB   = tid + 256;
    const bool hasB = (sB < NSLOT);
    const int  rB   = sB / 40;
    const int  cB   = sB - rB * 40;
    const int  gyB  = y0 - 1 + rB;
    const bool vB   = hasB && (gyB >= 0) && (gyB < NH);
    const int  gyBc = min(max(gyB, 0), NH - 1);

    // All loads into named registers, issued back-to-back (one latency
    // exposure); default VGPR budget keeps them resident (no scratch).
    const float4* ppA = (const float4*)(pred + pbase + (size_t)gyAc * NW) + cA;
    const float4 a0 = ppA[0];
    const float4 a1 = ppA[cs4];
    const float4 a2 = ppA[2 * cs4];
    const float4 a3 = ppA[3 * cs4];
    const int4   ta = ((const int4*)(target + tbase + (size_t)gyAc * NW))[cA];

    const int cBs  = hasB ? cB : 0;   // safe address for inactive threads
    const int gyBs = hasB ? gyBc : 0;
    const float4* ppB = (const float4*)(pred + pbase + (size_t)gyBs * NW) + cBs;
    const float4 b0 = ppB[0];
    const float4 b1 = ppB[cs4];
    const float4 b2 = ppB[2 * cs4];
    const float4 b3 = ppB[3 * cs4];
    const int4   tb = ((const int4*)(target + tbase + (size_t)gyBs * NW))[cBs];

    // ---- Softmax + pack + stage: one b128 per plane per slot ----
    {
        uint4 wa, wb;
        qcalc(a0.x, a1.x, a2.x, a3.x, ta.x, vA, wa.x, wb.x);
        qcalc(a0.y, a1.y, a2.y, a3.y, ta.y, vA, wa.y, wb.y);
        qcalc(a0.z, a1.z, a2.z, a3.z, ta.z, vA, wa.z, wb.z);
        qcalc(a0.w, a1.w, a2.w, a3.w, ta.w, vA, wa.w, wb.w);
        ((uint4*)pa)[rA * 40 + cA] = wa;   // 16-B lane stride: conflict-free
        ((uint4*)pb)[rA * 40 + cA] = wb;
    }
    if (hasB) {
        uint4 wa, wb;
        qcalc(b0.x, b1.x, b2.x, b3.x, tb.x, vB, wa.x, wb.x);
        qcalc(b0.y, b1.y, b2.y, b3.y, tb.y, vB, wa.y, wb.y);
        qcalc(b0.z, b1.z, b2.z, b3.z, tb.z, vB, wa.z, wb.z);
        qcalc(b0.w, b1.w, b2.w, b3.w, tb.w, vB, wa.w, wb.w);
        ((uint4*)pa)[rB * 40 + cB] = wa;
        ((uint4*)pb)[rB * 40 + cB] = wb;
    }
    if (tid == 0) { pa[ZCELL] = 0u; pb[ZCELL] = 0u; }  // x-boundary guard
    __syncthreads();

    // ---- Vertical rolling Sobel (packed half2): column x = tid < 160 ----
    float acc = 0.f;
    if (tid < NW) {
        // branchless rolling addresses; boundary lanes pin l/r to ZCELL
        int am = tid;
        int al = (tid > 0)      ? tid - 1 : ZCELL;
        int ar = (tid < NW - 1) ? tid + 1 : ZCELL;
        const int il = (tid > 0)      ? NW : 0;
        const int ir = (tid < NW - 1) ? NW : 0;

        const __half2 two = __floats2half2_rn(2.f, 2.f);
        const __half2 hz  = __floats2half2_rn(0.f, 0.f);
        __half2 smmA = hz, smA = hz, dmmA = hz, dmA = hz;
        __half2 smmB = hz, smB = hz, dmmB = hz, dmB = hz;

#define CLS(P, smm, sm, dmm, dm)                                          \
        do {                                                              \
            const __half2 l = ld_h2(P, al);                               \
            const __half2 m = ld_h2(P, am);                               \
            const __half2 r = ld_h2(P, ar);                               \
            const __half2 sn = __hadd2(__hfma2(m, two, l), r);            \
            const __half2 dn = __hsub2(r, l);                             \
            if (t >= 2) {                                                 \
                const __half2 gx = __hadd2(__hfma2(dm, two, dmm), dn);    \
                const __half2 gy = __hsub2(sn, smm);                      \
                const __half2 rs = __hfma2(__hmul2(gy, gy), two,          \
                                           __hmul2(gx, gx));              \
                acc += __low2float(rs) + __high2float(rs);                \
            }                                                             \
            smm = sm; sm = sn; dmm = dm; dm = dn;                         \
        } while (0)

        #pragma unroll
        for (int t = 0; t < SR; ++t) {
            CLS(pa, smmA, smA, dmmA, dmA);
            CLS(pb, smmB, smB, dmmB, dmB);
            am += NW; al += il; ar += ir;
        }
#undef CLS
    }

    // ---- Block reduction -> ONE PLAIN STORE per block (no atomics) ----
    #pragma unroll
    for (int off = 32; off > 0; off >>= 1)
        acc += __shfl_down(acc, off, 64);
    if ((tid & 63) == 0) wsum[tid >> 6] = acc;
    __syncthreads();
    if (tid == 0) {
        part[lin] = wsum[0] + wsum[1] + wsum[2] + wsum[3];
    }
}

__global__ __launch_bounds__(256) void reduce_partials_kernel(
    const float* __restrict__ part, float* __restrict__ out)
{
    const int tid = threadIdx.x;
    const float4* p4 = (const float4*)part;   // NBLK/4 = 768 float4
    float s = 0.f;
    #pragma unroll
    for (int i = 0; i < NBLK / 1024; ++i) {   // 3 coalesced b128 loads
        const float4 v = p4[tid + i * 256];
        s += (v.x + v.y) + (v.z + v.w);
    }
    #pragma unroll
    for (int off = 32; off > 0; off >>= 1)
        s += __shfl_down(s, off, 64);
    __shared__ float wsum[4];
    if ((tid & 63) == 0) wsum[tid >> 6] = s;
    __syncthreads();
    if (tid == 0)
        out[0] = (wsum[0] + wsum[1] + wsum[2] + wsum[3]) * SCALE;
}

extern "C" void kernel_launch(void* const* d_in, const int* in_sizes, int n_in,
                              void* d_out, int out_size, void* d_ws, size_t ws_size,
                              hipStream_t stream) {
    const float* pred   = (const float*)d_in[0];
    const int*   target = (const int*)d_in[1];
    float*       out    = (float*)d_out;
    float*       part   = (float*)d_ws;      // NBLK*4 = 12 KB of scratch

    boundary_loss_kernel<<<dim3(NBLK), 256, 0, stream>>>(pred, target, part);
    reduce_partials_kernel<<<1, 256, 0, stream>>>(part, out);
}